// Round 4
// baseline (304.325 us; speedup 1.0000x reference)
//
#include <hip/hip_runtime.h>
#include <hip/hip_bf16.h>

#define SEQ 2048
#define DMODEL 2048
#define NHEAD 8
#define DHEAD 256

typedef _Float16 v8h __attribute__((ext_vector_type(8)));
typedef unsigned short v8u __attribute__((ext_vector_type(8)));
typedef float v4f __attribute__((ext_vector_type(4)));

__device__ __forceinline__ float b2f(unsigned short s) {
    return __uint_as_float(((unsigned)s) << 16);
}
__device__ __forceinline__ unsigned short f2b(float f) {
    unsigned u = __float_as_uint(f);
    u += 0x7fffu + ((u >> 16) & 1u);   // RNE
    return (unsigned short)(u >> 16);
}
__device__ __forceinline__ unsigned short f2h(float f) {
    _Float16 h = (_Float16)f;
    return __builtin_bit_cast(unsigned short, h);
}
__device__ __forceinline__ float h2f(unsigned short s) {
    return (float)__builtin_bit_cast(_Float16, s);
}

// ---------------------------------------------------------------- detect dtype
__global__ __launch_bounds__(256) void k_detect(const unsigned short* q, int* flag) {
    __shared__ int cnt;
    if (threadIdx.x == 0) cnt = 0;
    __syncthreads();
    int wild = 0;
    for (int i = threadIdx.x; i < 2048; i += 256) {
        float x = b2f(q[i]);
        float ax = fabsf(x);
        if (!(ax <= 100.0f) || (x != 0.0f && ax < 1e-6f)) wild++;
    }
    atomicAdd(&cnt, wild);
    __syncthreads();
    if (threadIdx.x == 0) *flag = (cnt < 256) ? 1 : 0;  // 1 = bf16, 0 = f32
}

// ----------------------------------------------- convert q, k -> fp16 (coalesced)
__global__ __launch_bounds__(256) void k_cvt_qk(const void* q, const void* k,
                                                const int* flag,
                                                unsigned short* qb, unsigned short* kb) {
    int bf = *(volatile const int*)flag;
    size_t i0 = ((size_t)blockIdx.x * 256 + threadIdx.x) * 8;
    v8u oq, ok;
    if (bf) {
        v8u uq = *(const v8u*)((const unsigned short*)q + i0);
        v8u uk = *(const v8u*)((const unsigned short*)k + i0);
#pragma unroll
        for (int j = 0; j < 8; j++) {
            oq[j] = f2h(b2f(uq[j]));
            ok[j] = f2h(b2f(uk[j]));
        }
    } else {
        const float* qf = (const float*)q;
        const float* kf = (const float*)k;
        v4f q0 = *(const v4f*)(qf + i0), q1 = *(const v4f*)(qf + i0 + 4);
        v4f k0 = *(const v4f*)(kf + i0), k1 = *(const v4f*)(kf + i0 + 4);
#pragma unroll
        for (int j = 0; j < 4; j++) {
            oq[j] = f2h(q0[j]); oq[4 + j] = f2h(q1[j]);
            ok[j] = f2h(k0[j]); ok[4 + j] = f2h(k1[j]);
        }
    }
    *(v8u*)(qb + i0) = oq;
    *(v8u*)(kb + i0) = ok;
}

// ----------------------------------------------------------- out_weight -> f32
__global__ __launch_bounds__(256) void k_cvt_gw(const void* ow, const int* flag, float* gw) {
    int bf = *(volatile const int*)flag;
    int i = blockIdx.x * 256 + threadIdx.x;
    gw[i] = bf ? b2f(((const unsigned short*)ow)[i]) : ((const float*)ow)[i];
}

// ------------------------------------------- v -> vT[h][d][s] fp16 (transposed)
__global__ __launch_bounds__(256) void k_tr_v(const void* v, const int* flag,
                                              unsigned short* vT) {
    __shared__ unsigned short tile[64][72];
    int bf = *(volatile const int*)flag;
    int s0 = blockIdx.x * 64, d0 = blockIdx.y * 64;
    int r = threadIdx.x >> 2, c0 = (threadIdx.x & 3) * 16;
    size_t base = (size_t)(s0 + r) * DMODEL + d0 + c0;
    if (bf) {
        const unsigned short* vp = (const unsigned short*)v;
        v8u a = *(const v8u*)(vp + base);
        v8u b = *(const v8u*)(vp + base + 8);
#pragma unroll
        for (int j = 0; j < 8; j++) { tile[r][c0 + j] = f2h(b2f(a[j])); tile[r][c0 + 8 + j] = f2h(b2f(b[j])); }
    } else {
        const float* vp = (const float*)v;
        v4f a0 = *(const v4f*)(vp + base), a1 = *(const v4f*)(vp + base + 4);
        v4f a2 = *(const v4f*)(vp + base + 8), a3 = *(const v4f*)(vp + base + 12);
#pragma unroll
        for (int j = 0; j < 4; j++) {
            tile[r][c0 + j]      = f2h(a0[j]);
            tile[r][c0 + 4 + j]  = f2h(a1[j]);
            tile[r][c0 + 8 + j]  = f2h(a2[j]);
            tile[r][c0 + 12 + j] = f2h(a3[j]);
        }
    }
    __syncthreads();
    int dr = threadIdx.x >> 2, sc0 = (threadIdx.x & 3) * 16;
    v8u o0, o1;
#pragma unroll
    for (int j = 0; j < 8; j++) { o0[j] = tile[sc0 + j][dr]; o1[j] = tile[sc0 + 8 + j][dr]; }
    int head = d0 >> 8;
    int dh = (d0 & 255) + dr;
    size_t ob = ((size_t)head * DHEAD + dh) * SEQ + s0 + sc0;
    *(v8u*)(vT + ob) = o0;
    *(v8u*)(vT + ob + 8) = o1;
}

// --------------------------------------------- gate pre-activations (f32)
// grid (64 s-chunks, 8 d-chunks). Weights staged in LDS (they were the
// latency hog: 1536 scalar strided global loads per thread before).
__global__ __launch_bounds__(256) void k_gates(const void* q, const void* k, const void* v,
                                               const void* igk, const void* fgk,
                                               const int* flag, float* ipre, float* fpre) {
    __shared__ float x_lds[32][68];
    __shared__ float w_lds[2][64][8];
    int bf = *(volatile const int*)flag;
    int s0 = blockIdx.x * 32;
    int c  = blockIdx.y;
    int tid = threadIdx.x;
    int sl = tid >> 3, hh = tid & 7;
    int rr = tid >> 3, j0 = (tid & 7) * 8;
    int g = tid >> 7, rem = tid & 127, jj = rem >> 1, hf = (rem & 1) * 4;
    float accI = 0.f, accF = 0.f;
    for (int wd = 0; wd < 12; ++wd) {
        int gd0 = c * 768 + wd * 64;
        const void* src; int off;
        if (gd0 < 2048)      { src = q; off = gd0; }
        else if (gd0 < 4096) { src = k; off = gd0 - 2048; }
        else                 { src = v; off = gd0 - 4096; }
        __syncthreads();
        size_t base = (size_t)(s0 + rr) * DMODEL + off + j0;
        if (bf) {
            const unsigned short* sp = (const unsigned short*)src;
            v8u a = *(const v8u*)(sp + base);
#pragma unroll
            for (int j = 0; j < 8; j++) x_lds[rr][j0 + j] = b2f(a[j]);
        } else {
            const float* sp = (const float*)src;
            v4f a0 = *(const v4f*)(sp + base), a1 = *(const v4f*)(sp + base + 4);
#pragma unroll
            for (int j = 0; j < 4; j++) { x_lds[rr][j0 + j] = a0[j]; x_lds[rr][j0 + 4 + j] = a1[j]; }
        }
        {
            const void* wsrc = g ? fgk : igk;
            int wb = (gd0 + jj) * NHEAD + hf;
            if (bf) {
                const unsigned short* wp = (const unsigned short*)wsrc;
#pragma unroll
                for (int u = 0; u < 4; u++) w_lds[g][jj][hf + u] = b2f(wp[wb + u]);
            } else {
                const float* wp = (const float*)wsrc;
                v4f wv = *(const v4f*)(wp + wb);
#pragma unroll
                for (int u = 0; u < 4; u++) w_lds[g][jj][hf + u] = wv[u];
            }
        }
        __syncthreads();
#pragma unroll 8
        for (int j = 0; j < 64; j++) {
            float x = x_lds[sl][j];
            accI += x * w_lds[0][j][hh];
            accF += x * w_lds[1][j][hh];
        }
    }
    atomicAdd(&ipre[hh * SEQ + s0 + sl], accI);
    atomicAdd(&fpre[hh * SEQ + s0 + sl], accF);
}

// ---------------- per-head scans: cum(log_sigmoid(f)), a = i - cum, prefix-max
__global__ __launch_bounds__(256) void k_scan(const float* ipre, const float* fpre,
                                              const void* ib_, const void* fb_,
                                              const int* flag,
                                              float* a_g, float* amax_g) {
    __shared__ float sarr[256];
    int bf = *(volatile const int*)flag;
    int h = blockIdx.x, tid = threadIdx.x;
    float ib = bf ? b2f(((const unsigned short*)ib_)[h]) : ((const float*)ib_)[h];
    float fb = bf ? b2f(((const unsigned short*)fb_)[h]) : ((const float*)fb_)[h];
    int s0 = tid * 8;
    float lf[8], ip[8];
#pragma unroll
    for (int j = 0; j < 8; j++) {
        float fp = fpre[h * SEQ + s0 + j] + fb;
        lf[j] = fminf(fp, 0.0f) - log1pf(__expf(-fabsf(fp)));
        ip[j] = ipre[h * SEQ + s0 + j] + ib;
    }
    float cs[8]; float t = 0.f;
#pragma unroll
    for (int j = 0; j < 8; j++) { t += lf[j]; cs[j] = t; }
    sarr[tid] = t; __syncthreads();
    for (int ofs = 1; ofs < 256; ofs <<= 1) {
        float val = sarr[tid];
        if (tid >= ofs) val += sarr[tid - ofs];
        __syncthreads(); sarr[tid] = val; __syncthreads();
    }
    float excl = (tid > 0) ? sarr[tid - 1] : 0.0f;
    float cum[8], av[8];
#pragma unroll
    for (int j = 0; j < 8; j++) { cum[j] = excl + cs[j]; av[j] = ip[j] - cum[j]; }
    float mx = av[0];
#pragma unroll
    for (int j = 1; j < 8; j++) mx = fmaxf(mx, av[j]);
    __syncthreads(); sarr[tid] = mx; __syncthreads();
    for (int ofs = 1; ofs < 256; ofs <<= 1) {
        float val = sarr[tid];
        if (tid >= ofs) val = fmaxf(val, sarr[tid - ofs]);
        __syncthreads(); sarr[tid] = val; __syncthreads();
    }
    float run = (tid > 0) ? sarr[tid - 1] : -3.0e38f;
#pragma unroll
    for (int j = 0; j < 8; j++) {
        run = fmaxf(run, av[j]);
        int s = s0 + j;
        a_g[h * SEQ + s]    = av[j];
        amax_g[h * SEQ + s] = run;
    }
}

// --------------------------------------------------------------- main kernel
// One wave per block (64 thr). t-strip = 16 rows. Everything streamed from
// global (K/V B-frags are 16B-contiguous in kb/vT); K register-double-buffered.
// Only P's C->A transform round-trips per-wave LDS -> ZERO barriers.
// Row scale (normalizer n, stabilizer exp(-m)) dropped: LayerNorm is
// invariant to positive per-row scaling (eps perturbation ~1e-6).
__global__ __launch_bounds__(64, 1) void k_main(const unsigned short* __restrict__ qb,
                                                const unsigned short* __restrict__ kb,
                                                const unsigned short* __restrict__ vT,
                                                const float* __restrict__ a_g,
                                                const float* __restrict__ amax_g,
                                                const float* __restrict__ gw,
                                                const int* flag, void* out) {
    // stride 36 shorts = 18 dwords: qd-step = 72 dwords == 8 mod 32 -> conflict-free
    __shared__ __align__(16) unsigned short P_hi[16][36];
    __shared__ __align__(16) unsigned short P_lo[16][36];

    const int bid  = blockIdx.x;          // 0..1023
    const int T    = 127 - (bid >> 3);    // long strips dispatch first
    const int h    = bid & 7;
    const int t0   = T * 16;
    const int lane = threadIdx.x;
    const int l15  = lane & 15;
    const int qd   = lane >> 4;           // quad 0..3
    const int hd0  = h * DHEAD;
    const int hSEQ = h * SEQ;
    const int nS   = (T + 2) >> 1;        // number of 32-col s-tiles
    const int bf   = *(volatile const int*)flag;

    // persistent q A-frags (16 rows x 256 d)
    v8h qf[8];
    {
        const unsigned short* qp = qb + (size_t)(t0 + l15) * DMODEL + hd0 + qd * 8;
#pragma unroll
        for (int d = 0; d < 8; d++) qf[d] = *(const v8h*)(qp + d * 32);
    }
    float amax[4];
#pragma unroll
    for (int r = 0; r < 4; r++) amax[r] = amax_g[hSEQ + t0 + qd * 4 + r];

    const unsigned short* kp = kb + (size_t)l15 * DMODEL + hd0 + qd * 8;
    const unsigned short* vp = vT + (size_t)(hd0 + l15) * SEQ + qd * 8;

    const v4f vzero = {0.f, 0.f, 0.f, 0.f};
    v4f acc[16];
#pragma unroll
    for (int nn = 0; nn < 16; nn++) acc[nn] = vzero;

    v8h kfA[16], kfB[16];
#pragma unroll
    for (int nt = 0; nt < 2; nt++)
#pragma unroll
        for (int d = 0; d < 8; d++)
            kfA[nt * 8 + d] = *(const v8h*)(kp + (size_t)(nt * 16) * DMODEL + d * 32);

#define HALF(KC, KN)                                                                     \
    do {                                                                                 \
        const int s0 = js * 32;                                                          \
        v8h vf[16];                                                                      \
        _Pragma("unroll") for (int nn = 0; nn < 16; nn++)                                \
            vf[nn] = *(const v8h*)(vp + (size_t)(nn * 16) * SEQ + s0);                   \
        float a0 = a_g[hSEQ + s0 + l15];                                                 \
        float a1 = a_g[hSEQ + s0 + 16 + l15];                                            \
        v4f c0 = vzero, c1 = vzero;                                                      \
        _Pragma("unroll") for (int d = 0; d < 8; d++) {                                  \
            c0 = __builtin_amdgcn_mfma_f32_16x16x32_f16(qf[d], KC[d], c0, 0, 0, 0);      \
            c1 = __builtin_amdgcn_mfma_f32_16x16x32_f16(qf[d], KC[8 + d], c1, 0, 0, 0);  \
        }                                                                                \
        const bool last = (js == nS - 1);                                                \
        _Pragma("unroll") for (int r = 0; r < 4; r++) {                                  \
            int row = qd * 4 + r, trow = t0 + row;                                       \
            float v0 = c0[r] * 0.0625f * __expf(fminf(a0 - amax[r], 0.f));               \
            float v1 = c1[r] * 0.0625f * __expf(fminf(a1 - amax[r], 0.f));               \
            if (last && (s0 + l15 > trow)) v0 = 0.f;                                     \
            if (last && (s0 + 16 + l15 > trow)) v1 = 0.f;                                \
            unsigned short h0 = f2h(v0), h1 = f2h(v1);                                   \
            P_hi[row][l15] = h0;      P_hi[row][16 + l15] = h1;                          \
            P_lo[row][l15] = f2h(v0 - h2f(h0));                                          \
            P_lo[row][16 + l15] = f2h(v1 - h2f(h1));                                     \
        }                                                                                \
        if (js + 1 < nS) {                                                               \
            _Pragma("unroll") for (int nt = 0; nt < 2; nt++)                             \
            _Pragma("unroll") for (int d = 0; d < 8; d++)                                 \
                KN[nt * 8 + d] =                                                         \
                    *(const v8h*)(kp + (size_t)(s0 + 32 + nt * 16) * DMODEL + d * 32);   \
        }                                                                                \
        v8h aH = *(const v8h*)&P_hi[l15][qd * 8];                                        \
        v8h aL = *(const v8h*)&P_lo[l15][qd * 8];                                        \
        _Pragma("unroll") for (int nn = 0; nn < 16; nn++) {                              \
            acc[nn] = __builtin_amdgcn_mfma_f32_16x16x32_f16(aH, vf[nn], acc[nn], 0, 0, 0); \
            acc[nn] = __builtin_amdgcn_mfma_f32_16x16x32_f16(aL, vf[nn], acc[nn], 0, 0, 0); \
        }                                                                                \
    } while (0)

    int js = 0;
    for (;;) {
        HALF(kfA, kfB);
        if (++js >= nS) break;
        HALF(kfB, kfA);
        if (++js >= nS) break;
    }
#undef HALF

    // ---- epilogue: per-row LayerNorm, all in-register (16-lane shuffle groups)
    float gwv[16];
#pragma unroll
    for (int nn = 0; nn < 16; nn++) gwv[nn] = gw[hd0 + nn * 16 + l15];
#pragma unroll
    for (int r = 0; r < 4; r++) {
        float sm = 0.f, sq = 0.f;
#pragma unroll
        for (int nn = 0; nn < 16; nn++) { float x = acc[nn][r]; sm += x; sq += x * x; }
#pragma unroll
        for (int m = 1; m < 16; m <<= 1) {
            sm += __shfl_xor(sm, m, 64);
            sq += __shfl_xor(sq, m, 64);
        }
        float mean = sm * (1.0f / 256.0f);
        float var  = fmaxf(sq * (1.0f / 256.0f) - mean * mean, 0.0f);
        float rstd = rsqrtf(var + 1e-6f);
        size_t ob = (size_t)(t0 + qd * 4 + r) * DMODEL + hd0 + l15;
        if (bf) {
            unsigned short* o = (unsigned short*)out;
#pragma unroll
            for (int nn = 0; nn < 16; nn++)
                o[ob + nn * 16] = f2b((acc[nn][r] - mean) * rstd * gwv[nn]);
        } else {
            float* o = (float*)out;
#pragma unroll
            for (int nn = 0; nn < 16; nn++)
                o[ob + nn * 16] = (acc[nn][r] - mean) * rstd * gwv[nn];
        }
    }
}

// ---------------------------------------------------------------------- host
extern "C" void kernel_launch(void* const* d_in, const int* in_sizes, int n_in,
                              void* d_out, int out_size, void* d_ws, size_t ws_size,
                              hipStream_t stream) {
    const void* q   = d_in[0];
    const void* k   = d_in[1];
    const void* v   = d_in[2];
    const void* igk = d_in[3];
    const void* igb = d_in[4];
    const void* fgk = d_in[5];
    const void* fgb = d_in[6];
    const void* ow  = d_in[7];

    char* ws = (char*)d_ws;
    int*   flag   = (int*)(ws + 0);
    float* ipre   = (float*)(ws + 1024);
    float* fpre   = (float*)(ws + 1024 + 1 * 65536);
    float* a_g    = (float*)(ws + 1024 + 2 * 65536);
    float* amax_g = (float*)(ws + 1024 + 3 * 65536);
    float* gw     = (float*)(ws + 1024 + 4 * 65536);
    unsigned short* qb = (unsigned short*)(ws + 1024 + 4 * 65536 + 8192);
    unsigned short* kb = qb + (size_t)SEQ * DMODEL;
    unsigned short* vT = kb + (size_t)SEQ * DMODEL;

    hipMemsetAsync(ipre, 0, 2 * 65536, stream);
    k_detect<<<1, 256, 0, stream>>>((const unsigned short*)q, flag);
    k_cvt_qk<<<2048, 256, 0, stream>>>(q, k, flag, qb, kb);
    k_cvt_gw<<<8, 256, 0, stream>>>(ow, flag, gw);
    k_tr_v<<<dim3(32, 32), 256, 0, stream>>>(v, flag, vT);
    k_gates<<<dim3(64, 8), 256, 0, stream>>>(q, k, v, igk, fgk, flag, ipre, fpre);
    k_scan<<<8, 256, 0, stream>>>(ipre, fpre, igb, fgb, flag, a_g, amax_g);
    k_main<<<1024, 64, 0, stream>>>(qb, kb, vT, a_g, amax_g, gw, flag, d_out);
}